// Round 1
// baseline (1709.849 us; speedup 1.0000x reference)
//
#include <hip/hip_runtime.h>
#include <hip/hip_bf16.h>

// ---------- types & helpers ----------
typedef __attribute__((ext_vector_type(8))) short      bf16x8;  // 8 bf16 = 4 VGPRs
typedef __attribute__((ext_vector_type(4))) float      f32x4;
typedef __attribute__((ext_vector_type(8))) unsigned short u16x8;

__device__ __forceinline__ unsigned short f2bf(float f) {
    union { __hip_bfloat16 h; unsigned short u; } cv;
    cv.h = __float2bfloat16(f);
    return cv.u;
}
__device__ __forceinline__ float bf2f(unsigned short u) {
    union { float f; unsigned int i; } cv;
    cv.i = ((unsigned int)u) << 16;
    return cv.f;
}
__device__ __forceinline__ void gload_lds16(const void* g, void* l) {
    __builtin_amdgcn_global_load_lds(
        (const __attribute__((address_space(1))) void*)g,
        (__attribute__((address_space(3))) void*)l, 16, 0, 0);
}
__device__ __forceinline__ f32x4 mfma16(bf16x8 a, bf16x8 b, f32x4 c) {
    return __builtin_amdgcn_mfma_f32_16x16x32_bf16(a, b, c, 0, 0, 0);
}
__device__ __forceinline__ float gelu_f(float x) {
    return 0.5f * x * (1.0f + erff(x * 0.70710678118654752f));
}

// ---------- LayerNorm: one block per row of 2048, out = bf16 ----------
template<int IN_BF16>
__global__ __launch_bounds__(256) void ln_kernel(const void* in, const float* w, const float* b,
                                                 unsigned short* out) {
    const int row = blockIdx.x;
    const int tid = threadIdx.x;
    float v[8];
    if constexpr (IN_BF16) {
        const unsigned short* p = (const unsigned short*)in + (size_t)row * 2048 + tid * 8;
        u16x8 raw = *(const u16x8*)p;
#pragma unroll
        for (int j = 0; j < 8; j++) v[j] = bf2f(raw[j]);
    } else {
        const float* p = (const float*)in + (size_t)row * 2048 + tid * 8;
        float4 a = ((const float4*)p)[0];
        float4 c = ((const float4*)p)[1];
        v[0] = a.x; v[1] = a.y; v[2] = a.z; v[3] = a.w;
        v[4] = c.x; v[5] = c.y; v[6] = c.z; v[7] = c.w;
    }
    float s = 0.f, ss = 0.f;
#pragma unroll
    for (int j = 0; j < 8; j++) { s += v[j]; ss += v[j] * v[j]; }
#pragma unroll
    for (int off = 32; off > 0; off >>= 1) {
        s  += __shfl_xor(s, off);
        ss += __shfl_xor(ss, off);
    }
    __shared__ float red[8];
    const int wid = tid >> 6, lane = tid & 63;
    if (lane == 0) { red[wid] = s; red[4 + wid] = ss; }
    __syncthreads();
    s  = red[0] + red[1] + red[2] + red[3];
    ss = red[4] + red[5] + red[6] + red[7];
    const float mean = s * (1.0f / 2048.0f);
    const float var  = ss * (1.0f / 2048.0f) - mean * mean;
    const float rstd = rsqrtf(var + 1e-5f);
    unsigned short* op = out + (size_t)row * 2048 + tid * 8;
    u16x8 ov;
#pragma unroll
    for (int j = 0; j < 8; j++) {
        int c = tid * 8 + j;
        ov[j] = f2bf((v[j] - mean) * rstd * w[c] + b[c]);
    }
    *(u16x8*)op = ov;
}

// ---------- Weight transpose+convert: W[K][N] f32 -> WT[N][K] bf16 ----------
__global__ __launch_bounds__(256) void wt_kernel(const float* W, unsigned short* WT, int K, int N) {
    __shared__ unsigned short sm[32][33];
    const int n0 = blockIdx.x * 32, k0 = blockIdx.y * 32;
    const int tx = threadIdx.x, ty = threadIdx.y;
#pragma unroll
    for (int i = 0; i < 4; i++) {
        int k = ty + i * 8;
        sm[k][tx] = f2bf(W[(size_t)(k0 + k) * N + n0 + tx]);
    }
    __syncthreads();
#pragma unroll
    for (int i = 0; i < 4; i++) {
        int n = ty + i * 8;
        WT[(size_t)(n0 + n) * K + k0 + tx] = sm[tx][n];
    }
}

// ---------- V transpose: qkv bf16 -> vT[b][h][128][2048] bf16 ----------
__global__ __launch_bounds__(256) void vt_kernel(const unsigned short* qkv, unsigned short* vT) {
    __shared__ unsigned short sm[32][33];
    const int t0 = blockIdx.x * 32, d0 = blockIdx.y * 32, bh = blockIdx.z;
    const int b = bh >> 4, h = bh & 15;
    const int tx = threadIdx.x, ty = threadIdx.y;
#pragma unroll
    for (int i = 0; i < 4; i++) {
        int t = ty + i * 8;
        sm[t][tx] = qkv[(size_t)(b * 2048 + t0 + t) * 6144 + 4096 + h * 128 + d0 + tx];
    }
    __syncthreads();
#pragma unroll
    for (int i = 0; i < 4; i++) {
        int d = ty + i * 8;
        vT[(size_t)(bh * 128 + d0 + d) * 2048 + t0 + tx] = sm[tx][d];
    }
}

// ---------- GEMM: C[M][N] = A[M][K](bf16) * BT[N][K](bf16)^T + bias ----------
// m97 structure: 128x128 tile, BK=32, 4 waves (2x2), 4x4 16x16 frags per wave.
template<int OUT_BF16, int ACT_GELU>
__global__ __launch_bounds__(256) void gemm_bt(const unsigned short* __restrict__ A,
                                               const unsigned short* __restrict__ BT,
                                               const float* __restrict__ bias,
                                               void* __restrict__ Cout,
                                               int M, int N, int K) {
    __shared__ unsigned short As[128 * 32];
    __shared__ unsigned short Bs[128 * 32];
    const int tid = threadIdx.x;
    const int n0 = blockIdx.x * 128, m0 = blockIdx.y * 128;
    const int wid = tid >> 6, lane = tid & 63;
    const int wr = wid >> 1, wc = wid & 1;
    const int lg = lane >> 4, l15 = lane & 15;

    f32x4 acc[4][4] = {};

    for (int k0 = 0; k0 < K; k0 += 32) {
        __syncthreads();
#pragma unroll
        for (int i = 0; i < 2; i++) {
            int idx = tid + 256 * i;
            const unsigned short* g = A + (size_t)(m0 + (idx >> 2)) * K + k0 + (idx & 3) * 8;
            gload_lds16(g, &As[idx * 8]);
        }
#pragma unroll
        for (int i = 0; i < 2; i++) {
            int idx = tid + 256 * i;
            const unsigned short* g = BT + (size_t)(n0 + (idx >> 2)) * K + k0 + (idx & 3) * 8;
            gload_lds16(g, &Bs[idx * 8]);
        }
        __syncthreads();
        bf16x8 af[4], bfr[4];
#pragma unroll
        for (int m = 0; m < 4; m++)
            af[m] = *(const bf16x8*)&As[(wr * 64 + m * 16 + l15) * 32 + lg * 8];
#pragma unroll
        for (int n = 0; n < 4; n++)
            bfr[n] = *(const bf16x8*)&Bs[(wc * 64 + n * 16 + l15) * 32 + lg * 8];
#pragma unroll
        for (int m = 0; m < 4; m++)
#pragma unroll
            for (int n = 0; n < 4; n++)
                acc[m][n] = mfma16(af[m], bfr[n], acc[m][n]);
    }

#pragma unroll
    for (int n = 0; n < 4; n++) {
        const int col = n0 + wc * 64 + n * 16 + l15;
        const float bv = bias[col];
#pragma unroll
        for (int m = 0; m < 4; m++) {
            const int rbase = m0 + wr * 64 + m * 16 + lg * 4;
#pragma unroll
            for (int r = 0; r < 4; r++) {
                float v = acc[m][n][r] + bv;
                if (ACT_GELU) v = gelu_f(v);
                if (OUT_BF16)
                    ((unsigned short*)Cout)[(size_t)(rbase + r) * N + col] = f2bf(v);
                else
                    ((float*)Cout)[(size_t)(rbase + r) * N + col] = v;
            }
        }
    }
}

// ---------- Flash attention (causal). grid (qt=32, h=16, b=4), 256 thr ----------
__global__ __launch_bounds__(256) void attn_kernel(const unsigned short* __restrict__ qkv,
                                                   const unsigned short* __restrict__ vT,
                                                   unsigned short* __restrict__ y) {
    __shared__ unsigned short Qs[64 * 128];
    __shared__ unsigned short Ks[32 * 128];
    __shared__ unsigned short VTs[128 * 32];
    __shared__ unsigned short Ps[4 * 16 * 32];
    const int qt = blockIdx.x, h = blockIdx.y, b = blockIdx.z;
    const int tid = threadIdx.x, wid = tid >> 6, lane = tid & 63;
    const int lg = lane >> 4, l15 = lane & 15;

    // stage Q tile: 64 rows x 128
#pragma unroll
    for (int i = 0; i < 4; i++) {
        int idx = tid + 256 * i;
        int row = idx >> 4, ch = idx & 15;
        const unsigned short* g = qkv + (size_t)(b * 2048 + qt * 64 + row) * 6144 + h * 128 + ch * 8;
        gload_lds16(g, &Qs[idx * 8]);
    }
    __syncthreads();
    bf16x8 qf[4];
#pragma unroll
    for (int c = 0; c < 4; c++)
        qf[c] = *(const bf16x8*)&Qs[(wid * 16 + l15) * 128 + c * 32 + lg * 8];

    float m_run[4], l_run[4];
#pragma unroll
    for (int r = 0; r < 4; r++) { m_run[r] = -1e30f; l_run[r] = 0.f; }
    f32x4 O[8] = {};

    const float scale = 0.08838834764831845f;  // 1/sqrt(128)
    const int nkb = qt * 2 + 2;
    for (int kb = 0; kb < nkb; kb++) {
        __syncthreads();
        // stage K tile [32][128]
#pragma unroll
        for (int i = 0; i < 2; i++) {
            int idx = tid + 256 * i;
            int row = idx >> 4, ch = idx & 15;
            const unsigned short* g =
                qkv + (size_t)(b * 2048 + kb * 32 + row) * 6144 + 2048 + h * 128 + ch * 8;
            gload_lds16(g, &Ks[idx * 8]);
        }
        // stage VT tile [128][32]
#pragma unroll
        for (int i = 0; i < 2; i++) {
            int idx = tid + 256 * i;
            int row = idx >> 2, ch = idx & 3;
            const unsigned short* g =
                vT + (size_t)((b * 16 + h) * 128 + row) * 2048 + kb * 32 + ch * 8;
            gload_lds16(g, &VTs[idx * 8]);
        }
        __syncthreads();

        // S = Q K^T  (two 16-key col tiles)
        f32x4 S[2] = {};
#pragma unroll
        for (int n = 0; n < 2; n++)
#pragma unroll
            for (int c = 0; c < 4; c++) {
                bf16x8 kf = *(const bf16x8*)&Ks[(n * 16 + l15) * 128 + c * 32 + lg * 8];
                S[n] = mfma16(qf[c], kf, S[n]);
            }

        // online softmax (D-layout: row = lg*4+r, col = l15 / 16+l15)
        const int qg_base = qt * 64 + wid * 16 + lg * 4;
        const int kg0 = kb * 32 + l15, kg1 = kb * 32 + 16 + l15;
#pragma unroll
        for (int r = 0; r < 4; r++) {
            const int qg = qg_base + r;
            float s0 = (kg0 <= qg) ? S[0][r] * scale : -1e30f;
            float s1 = (kg1 <= qg) ? S[1][r] * scale : -1e30f;
            float mx = fmaxf(s0, s1);
            mx = fmaxf(mx, __shfl_xor(mx, 1));
            mx = fmaxf(mx, __shfl_xor(mx, 2));
            mx = fmaxf(mx, __shfl_xor(mx, 4));
            mx = fmaxf(mx, __shfl_xor(mx, 8));
            const float mnew = fmaxf(m_run[r], mx);
            const float f = __expf(m_run[r] - mnew);
            const float p0 = __expf(s0 - mnew);
            const float p1 = __expf(s1 - mnew);
            float rs = p0 + p1;
            rs += __shfl_xor(rs, 1);
            rs += __shfl_xor(rs, 2);
            rs += __shfl_xor(rs, 4);
            rs += __shfl_xor(rs, 8);
            l_run[r] = l_run[r] * f + rs;
            m_run[r] = mnew;
#pragma unroll
            for (int n2 = 0; n2 < 8; n2++) O[n2][r] *= f;
            Ps[wid * 512 + (lg * 4 + r) * 32 + l15]      = f2bf(p0);
            Ps[wid * 512 + (lg * 4 + r) * 32 + 16 + l15] = f2bf(p1);
        }
        __syncthreads();  // make P visible (also keeps staging phases aligned)

        // PV: O += P[16x32] * V[32x128]
        bf16x8 pf = *(const bf16x8*)&Ps[wid * 512 + l15 * 32 + lg * 8];
#pragma unroll
        for (int n2 = 0; n2 < 8; n2++) {
            bf16x8 vf = *(const bf16x8*)&VTs[(n2 * 16 + l15) * 32 + lg * 8];
            O[n2] = mfma16(pf, vf, O[n2]);
        }
    }

    // epilogue: normalize + store y bf16
#pragma unroll
    for (int r = 0; r < 4; r++) {
        const float inv = 1.0f / l_run[r];
        const size_t row = (size_t)(b * 2048 + qt * 64 + wid * 16 + lg * 4 + r);
#pragma unroll
        for (int n2 = 0; n2 < 8; n2++)
            y[row * 2048 + h * 128 + n2 * 16 + l15] = f2bf(O[n2][r] * inv);
    }
}

// ---------- launcher ----------
extern "C" void kernel_launch(void* const* d_in, const int* in_sizes, int n_in,
                              void* d_out, int out_size, void* d_ws, size_t ws_size,
                              hipStream_t stream) {
    const float* x      = (const float*)d_in[0];
    const float* ln1_w  = (const float*)d_in[1];
    const float* ln1_b  = (const float*)d_in[2];
    const float* attn_w = (const float*)d_in[3];
    const float* attn_b = (const float*)d_in[4];
    const float* ln2_w  = (const float*)d_in[5];
    const float* ln2_b  = (const float*)d_in[6];
    const float* fc_w   = (const float*)d_in[7];
    const float* fc_b   = (const float*)d_in[8];
    const float* proj_w = (const float*)d_in[9];
    const float* proj_b = (const float*)d_in[10];
    float* out = (float*)d_out;

    char* ws = (char*)d_ws;
    const size_t MB = 1024ull * 1024ull;
    unsigned short* Wt   = (unsigned short*)(ws + 0);         // 32MB: transposed weight (per phase)
    unsigned short* X1   = (unsigned short*)(ws + 32 * MB);   // 32MB: h / h2
    unsigned short* X2   = (unsigned short*)(ws + 64 * MB);   // 32MB: y
    unsigned short* QKV  = (unsigned short*)(ws + 96 * MB);   // 96MB: qkv bf16
    unsigned short* VT   = (unsigned short*)(ws + 192 * MB);  // 32MB: vT
    unsigned short* Abuf = (unsigned short*)(ws + 96 * MB);   // 128MB: gelu(fc) (reuses QKV+VT)

    // 1. h = ln1(x)
    ln_kernel<0><<<8192, 256, 0, stream>>>(x, ln1_w, ln1_b, X1);
    // 2. attn_w [2048][6144] -> Wt [6144][2048] bf16
    wt_kernel<<<dim3(6144 / 32, 2048 / 32), dim3(32, 8), 0, stream>>>(attn_w, Wt, 2048, 6144);
    // 3. qkv = h @ attn_w + attn_b  (bf16 out)
    gemm_bt<1, 0><<<dim3(48, 64), 256, 0, stream>>>(X1, Wt, attn_b, QKV, 8192, 6144, 2048);
    // 4. vT
    vt_kernel<<<dim3(64, 4, 64), dim3(32, 8), 0, stream>>>(QKV, VT);
    // 5. y = causal_attention(q,k,v)
    attn_kernel<<<dim3(32, 16, 4), 256, 0, stream>>>(QKV, VT, X2);
    // 6. h2 = ln2(y)
    ln_kernel<1><<<8192, 256, 0, stream>>>(X2, ln2_w, ln2_b, X1);
    // 7. fc_w [2048][8192] -> Wt [8192][2048]
    wt_kernel<<<dim3(8192 / 32, 2048 / 32), dim3(32, 8), 0, stream>>>(fc_w, Wt, 2048, 8192);
    // 8. a = gelu(h2 @ fc_w + fc_b) (bf16 out)
    gemm_bt<1, 1><<<dim3(64, 64), 256, 0, stream>>>(X1, Wt, fc_b, Abuf, 8192, 8192, 2048);
    // 9. proj_w [8192][2048] -> Wt [2048][8192]
    wt_kernel<<<dim3(2048 / 32, 8192 / 32), dim3(32, 8), 0, stream>>>(proj_w, Wt, 8192, 2048);
    // 10. out = a @ proj_w + proj_b (f32 out)
    gemm_bt<0, 0><<<dim3(16, 64), 256, 0, stream>>>(Abuf, Wt, proj_b, out, 8192, 2048, 8192);
}

// Round 2
// 1404.149 us; speedup vs baseline: 1.2177x; 1.2177x over previous
//
#include <hip/hip_runtime.h>
#include <hip/hip_bf16.h>

// ---------- types & helpers ----------
typedef __attribute__((ext_vector_type(8))) short      bf16x8;  // 8 bf16 = 4 VGPRs
typedef __attribute__((ext_vector_type(4))) float      f32x4;
typedef __attribute__((ext_vector_type(8))) unsigned short u16x8;

__device__ __forceinline__ unsigned short f2bf(float f) {
    union { __hip_bfloat16 h; unsigned short u; } cv;
    cv.h = __float2bfloat16(f);
    return cv.u;
}
__device__ __forceinline__ float bf2f(unsigned short u) {
    union { float f; unsigned int i; } cv;
    cv.i = ((unsigned int)u) << 16;
    return cv.f;
}
__device__ __forceinline__ void gload_lds16(const void* g, void* l) {
    __builtin_amdgcn_global_load_lds(
        (const __attribute__((address_space(1))) void*)g,
        (__attribute__((address_space(3))) void*)l, 16, 0, 0);
}
__device__ __forceinline__ f32x4 mfma16(bf16x8 a, bf16x8 b, f32x4 c) {
    return __builtin_amdgcn_mfma_f32_16x16x32_bf16(a, b, c, 0, 0, 0);
}
__device__ __forceinline__ float gelu_f(float x) {
    return 0.5f * x * (1.0f + erff(x * 0.70710678118654752f));
}

// ---------- LayerNorm: one block per row of 2048, out = bf16 ----------
template<int IN_BF16>
__global__ __launch_bounds__(256) void ln_kernel(const void* in, const float* w, const float* b,
                                                 unsigned short* out) {
    const int row = blockIdx.x;
    const int tid = threadIdx.x;
    float v[8];
    if constexpr (IN_BF16) {
        const unsigned short* p = (const unsigned short*)in + (size_t)row * 2048 + tid * 8;
        u16x8 raw = *(const u16x8*)p;
#pragma unroll
        for (int j = 0; j < 8; j++) v[j] = bf2f(raw[j]);
    } else {
        const float* p = (const float*)in + (size_t)row * 2048 + tid * 8;
        float4 a = ((const float4*)p)[0];
        float4 c = ((const float4*)p)[1];
        v[0] = a.x; v[1] = a.y; v[2] = a.z; v[3] = a.w;
        v[4] = c.x; v[5] = c.y; v[6] = c.z; v[7] = c.w;
    }
    float s = 0.f, ss = 0.f;
#pragma unroll
    for (int j = 0; j < 8; j++) { s += v[j]; ss += v[j] * v[j]; }
#pragma unroll
    for (int off = 32; off > 0; off >>= 1) {
        s  += __shfl_xor(s, off);
        ss += __shfl_xor(ss, off);
    }
    __shared__ float red[8];
    const int wid = tid >> 6, lane = tid & 63;
    if (lane == 0) { red[wid] = s; red[4 + wid] = ss; }
    __syncthreads();
    s  = red[0] + red[1] + red[2] + red[3];
    ss = red[4] + red[5] + red[6] + red[7];
    const float mean = s * (1.0f / 2048.0f);
    const float var  = ss * (1.0f / 2048.0f) - mean * mean;
    const float rstd = rsqrtf(var + 1e-5f);
    unsigned short* op = out + (size_t)row * 2048 + tid * 8;
    u16x8 ov;
#pragma unroll
    for (int j = 0; j < 8; j++) {
        int c = tid * 8 + j;
        ov[j] = f2bf((v[j] - mean) * rstd * w[c] + b[c]);
    }
    *(u16x8*)op = ov;
}

// ---------- Weight transpose+convert: W[K][N] f32 -> WT[N][K] bf16 ----------
__global__ __launch_bounds__(256) void wt_kernel(const float* W, unsigned short* WT, int K, int N) {
    __shared__ unsigned short sm[32][33];
    const int n0 = blockIdx.x * 32, k0 = blockIdx.y * 32;
    const int tx = threadIdx.x, ty = threadIdx.y;
#pragma unroll
    for (int i = 0; i < 4; i++) {
        int k = ty + i * 8;
        sm[k][tx] = f2bf(W[(size_t)(k0 + k) * N + n0 + tx]);
    }
    __syncthreads();
#pragma unroll
    for (int i = 0; i < 4; i++) {
        int n = ty + i * 8;
        WT[(size_t)(n0 + n) * K + k0 + tx] = sm[tx][n];
    }
}

// ---------- V transpose: qkv bf16 -> vT[b][h][128][2048] bf16 ----------
__global__ __launch_bounds__(256) void vt_kernel(const unsigned short* qkv, unsigned short* vT) {
    __shared__ unsigned short sm[32][33];
    const int t0 = blockIdx.x * 32, d0 = blockIdx.y * 32, bh = blockIdx.z;
    const int b = bh >> 4, h = bh & 15;
    const int tx = threadIdx.x, ty = threadIdx.y;
#pragma unroll
    for (int i = 0; i < 4; i++) {
        int t = ty + i * 8;
        sm[t][tx] = qkv[(size_t)(b * 2048 + t0 + t) * 6144 + 4096 + h * 128 + d0 + tx];
    }
    __syncthreads();
#pragma unroll
    for (int i = 0; i < 4; i++) {
        int d = ty + i * 8;
        vT[(size_t)(bh * 128 + d0 + d) * 2048 + t0 + tx] = sm[tx][d];
    }
}

// ---------- GEMM: C[M][N] = A[M][K](bf16) * BT[N][K](bf16)^T + bias ----------
// m97 structure + bijective XCD-aware block swizzle (grids here are %8==0).
template<int OUT_BF16, int ACT_GELU>
__global__ __launch_bounds__(256) void gemm_bt(const unsigned short* __restrict__ A,
                                               const unsigned short* __restrict__ BT,
                                               const float* __restrict__ bias,
                                               void* __restrict__ Cout,
                                               int M, int N, int K) {
    __shared__ unsigned short As[128 * 32];
    __shared__ unsigned short Bs[128 * 32];
    const int tid = threadIdx.x;
    const int gx = gridDim.x;
    const int lin = blockIdx.y * gx + blockIdx.x;
    const int cpx = (gx * gridDim.y) >> 3;
    const int swz = (lin & 7) * cpx + (lin >> 3);
    const int n0 = (swz % gx) * 128, m0 = (swz / gx) * 128;
    const int wid = tid >> 6, lane = tid & 63;
    const int wr = wid >> 1, wc = wid & 1;
    const int lg = lane >> 4, l15 = lane & 15;

    f32x4 acc[4][4] = {};

    for (int k0 = 0; k0 < K; k0 += 32) {
        __syncthreads();
#pragma unroll
        for (int i = 0; i < 2; i++) {
            int idx = tid + 256 * i;
            const unsigned short* g = A + (size_t)(m0 + (idx >> 2)) * K + k0 + (idx & 3) * 8;
            gload_lds16(g, &As[idx * 8]);
        }
#pragma unroll
        for (int i = 0; i < 2; i++) {
            int idx = tid + 256 * i;
            const unsigned short* g = BT + (size_t)(n0 + (idx >> 2)) * K + k0 + (idx & 3) * 8;
            gload_lds16(g, &Bs[idx * 8]);
        }
        __syncthreads();
        bf16x8 af[4], bfr[4];
#pragma unroll
        for (int m = 0; m < 4; m++)
            af[m] = *(const bf16x8*)&As[(wr * 64 + m * 16 + l15) * 32 + lg * 8];
#pragma unroll
        for (int n = 0; n < 4; n++)
            bfr[n] = *(const bf16x8*)&Bs[(wc * 64 + n * 16 + l15) * 32 + lg * 8];
#pragma unroll
        for (int m = 0; m < 4; m++)
#pragma unroll
            for (int n = 0; n < 4; n++)
                acc[m][n] = mfma16(af[m], bfr[n], acc[m][n]);
    }

#pragma unroll
    for (int n = 0; n < 4; n++) {
        const int col = n0 + wc * 64 + n * 16 + l15;
        const float bv = bias[col];
#pragma unroll
        for (int m = 0; m < 4; m++) {
            const int rbase = m0 + wr * 64 + m * 16 + lg * 4;
#pragma unroll
            for (int r = 0; r < 4; r++) {
                float v = acc[m][n][r] + bv;
                if (ACT_GELU) v = gelu_f(v);
                if (OUT_BF16)
                    ((unsigned short*)Cout)[(size_t)(rbase + r) * N + col] = f2bf(v);
                else
                    ((float*)Cout)[(size_t)(rbase + r) * N + col] = v;
            }
        }
    }
}

// ---------- Flash attention (causal), KVBLK=64, XOR-swizzled LDS ----------
// grid (pair=16, h=16, b=4), 256 thr. Each block does q-tiles (31-pair) and
// (pair): uniform 33 k-tiles per block.
__global__ __launch_bounds__(256) void attn_kernel(const unsigned short* __restrict__ qkv,
                                                   const unsigned short* __restrict__ vT,
                                                   unsigned short* __restrict__ y) {
    __shared__ unsigned short Qs[64 * 128];   // aliased as per-wave P after q-frag load
    __shared__ unsigned short Ks[64 * 128];
    __shared__ unsigned short VTs[128 * 64];
    const int pair = blockIdx.x, h = blockIdx.y, b = blockIdx.z;
    const int tid = threadIdx.x, wid = tid >> 6, lane = tid & 63;
    const int lg = lane >> 4, l15 = lane & 15;
    const float scale = 0.08838834764831845f;  // 1/sqrt(128)
    unsigned short* Ps = &Qs[wid * 1024];      // per-wave [16][64] swizzled

    for (int pass = 0; pass < 2; pass++) {
        const int qt = (pass == 0) ? (31 - pair) : pair;
        __syncthreads();  // previous pass fully consumed Q/P region
        // stage Q tile [64][128], source-swizzled so read-side XOR works
#pragma unroll
        for (int i = 0; i < 4; i++) {
            int idx = tid + 256 * i;
            int row = idx >> 4, ch = idx & 15;
            const unsigned short* g = qkv + (size_t)(b * 2048 + qt * 64 + row) * 6144
                                      + h * 128 + ((ch ^ (row & 7)) * 8);
            gload_lds16(g, &Qs[idx * 8]);
        }
        __syncthreads();
        const int rq = wid * 16 + l15;
        bf16x8 qf[4];
#pragma unroll
        for (int c = 0; c < 4; c++)
            qf[c] = *(const bf16x8*)&Qs[rq * 128 + (((c * 4 + lg) ^ (rq & 7)) * 8)];

        float m_run[4], l_run[4];
#pragma unroll
        for (int r = 0; r < 4; r++) { m_run[r] = -1e30f; l_run[r] = 0.f; }
        f32x4 O[8] = {};

        const int nkb = qt + 1;
        for (int kb = 0; kb < nkb; kb++) {
            __syncthreads();  // all waves done with previous K/V (and P region vs Q-stage)
            // K tile [64][128] swizzled
#pragma unroll
            for (int i = 0; i < 4; i++) {
                int idx = tid + 256 * i;
                int row = idx >> 4, ch = idx & 15;
                const unsigned short* g = qkv + (size_t)(b * 2048 + kb * 64 + row) * 6144
                                          + 2048 + h * 128 + ((ch ^ (row & 7)) * 8);
                gload_lds16(g, &Ks[idx * 8]);
            }
            // VT tile [128][64] swizzled
#pragma unroll
            for (int i = 0; i < 4; i++) {
                int idx = tid + 256 * i;
                int row = idx >> 3, ch = idx & 7;
                const unsigned short* g = vT + (size_t)((b * 16 + h) * 128 + row) * 2048
                                          + kb * 64 + ((ch ^ (row & 7)) * 8);
                gload_lds16(g, &VTs[idx * 8]);
            }
            __syncthreads();

            // S = Q K^T : 4 x 16-key col tiles
            f32x4 S[4] = {};
#pragma unroll
            for (int n = 0; n < 4; n++) {
                const int rk = n * 16 + l15;
#pragma unroll
                for (int c = 0; c < 4; c++) {
                    bf16x8 kf = *(const bf16x8*)&Ks[rk * 128 + (((c * 4 + lg) ^ (rk & 7)) * 8)];
                    S[n] = mfma16(qf[c], kf, S[n]);
                }
            }

            // online softmax; D-layout row = lg*4+r, col = n*16+l15
            const int qgb = qt * 64 + wid * 16 + lg * 4;
#pragma unroll
            for (int r = 0; r < 4; r++) {
                const int qg = qgb + r;
                float sv[4];
#pragma unroll
                for (int n = 0; n < 4; n++) {
                    const int kg = kb * 64 + n * 16 + l15;
                    sv[n] = (kg <= qg) ? S[n][r] * scale : -1e30f;
                }
                float mx = fmaxf(fmaxf(sv[0], sv[1]), fmaxf(sv[2], sv[3]));
                mx = fmaxf(mx, __shfl_xor(mx, 1));
                mx = fmaxf(mx, __shfl_xor(mx, 2));
                mx = fmaxf(mx, __shfl_xor(mx, 4));
                mx = fmaxf(mx, __shfl_xor(mx, 8));
                const float mnew = fmaxf(m_run[r], mx);
                const float f = __expf(m_run[r] - mnew);
                const float p0 = __expf(sv[0] - mnew), p1 = __expf(sv[1] - mnew);
                const float p2 = __expf(sv[2] - mnew), p3 = __expf(sv[3] - mnew);
                float rs = (p0 + p1) + (p2 + p3);
                rs += __shfl_xor(rs, 1);
                rs += __shfl_xor(rs, 2);
                rs += __shfl_xor(rs, 4);
                rs += __shfl_xor(rs, 8);
                l_run[r] = l_run[r] * f + rs;
                m_run[r] = mnew;
#pragma unroll
                for (int n2 = 0; n2 < 8; n2++) O[n2][r] *= f;
                const int prow = lg * 4 + r;
                const int pxor = (prow & 7) << 3;
                Ps[(prow * 64 + l15) ^ pxor]      = f2bf(p0);
                Ps[(prow * 64 + 16 + l15) ^ pxor] = f2bf(p1);
                Ps[(prow * 64 + 32 + l15) ^ pxor] = f2bf(p2);
                Ps[(prow * 64 + 48 + l15) ^ pxor] = f2bf(p3);
            }
            // P is wave-private: same-wave ds_write->ds_read ordered by lgkmcnt,
            // no __syncthreads needed here.

            // PV: O += P[16x64] * V[64x128]
#pragma unroll
            for (int kk = 0; kk < 2; kk++) {
                bf16x8 pf = *(const bf16x8*)&Ps[l15 * 64 + (((kk * 4 + lg) ^ (l15 & 7)) * 8)];
#pragma unroll
                for (int n2 = 0; n2 < 8; n2++) {
                    const int rv = n2 * 16 + l15;
                    bf16x8 vf = *(const bf16x8*)&VTs[rv * 64 + (((kk * 4 + lg) ^ (rv & 7)) * 8)];
                    O[n2] = mfma16(pf, vf, O[n2]);
                }
            }
        }

        // epilogue: normalize + store y bf16
#pragma unroll
        for (int r = 0; r < 4; r++) {
            const float inv = 1.0f / l_run[r];
            const size_t row = (size_t)(b * 2048 + qt * 64 + wid * 16 + lg * 4 + r);
#pragma unroll
            for (int n2 = 0; n2 < 8; n2++)
                y[row * 2048 + h * 128 + n2 * 16 + l15] = f2bf(O[n2][r] * inv);
        }
    }
}

// ---------- launcher ----------
extern "C" void kernel_launch(void* const* d_in, const int* in_sizes, int n_in,
                              void* d_out, int out_size, void* d_ws, size_t ws_size,
                              hipStream_t stream) {
    const float* x      = (const float*)d_in[0];
    const float* ln1_w  = (const float*)d_in[1];
    const float* ln1_b  = (const float*)d_in[2];
    const float* attn_w = (const float*)d_in[3];
    const float* attn_b = (const float*)d_in[4];
    const float* ln2_w  = (const float*)d_in[5];
    const float* ln2_b  = (const float*)d_in[6];
    const float* fc_w   = (const float*)d_in[7];
    const float* fc_b   = (const float*)d_in[8];
    const float* proj_w = (const float*)d_in[9];
    const float* proj_b = (const float*)d_in[10];
    float* out = (float*)d_out;

    char* ws = (char*)d_ws;
    const size_t MB = 1024ull * 1024ull;
    unsigned short* Wt   = (unsigned short*)(ws + 0);         // 32MB: transposed weight (per phase)
    unsigned short* X1   = (unsigned short*)(ws + 32 * MB);   // 32MB: h / h2
    unsigned short* X2   = (unsigned short*)(ws + 64 * MB);   // 32MB: y
    unsigned short* QKV  = (unsigned short*)(ws + 96 * MB);   // 96MB: qkv bf16
    unsigned short* VT   = (unsigned short*)(ws + 192 * MB);  // 32MB: vT
    unsigned short* Abuf = (unsigned short*)(ws + 96 * MB);   // 128MB: gelu(fc) (reuses QKV+VT)

    // 1. h = ln1(x)
    ln_kernel<0><<<8192, 256, 0, stream>>>(x, ln1_w, ln1_b, X1);
    // 2. attn_w [2048][6144] -> Wt [6144][2048] bf16
    wt_kernel<<<dim3(6144 / 32, 2048 / 32), dim3(32, 8), 0, stream>>>(attn_w, Wt, 2048, 6144);
    // 3. qkv = h @ attn_w + attn_b  (bf16 out)
    gemm_bt<1, 0><<<dim3(48, 64), 256, 0, stream>>>(X1, Wt, attn_b, QKV, 8192, 6144, 2048);
    // 4. vT
    vt_kernel<<<dim3(64, 4, 64), dim3(32, 8), 0, stream>>>(QKV, VT);
    // 5. y = causal_attention(q,k,v)
    attn_kernel<<<dim3(16, 16, 4), 256, 0, stream>>>(QKV, VT, X2);
    // 6. h2 = ln2(y)
    ln_kernel<1><<<8192, 256, 0, stream>>>(X2, ln2_w, ln2_b, X1);
    // 7. fc_w [2048][8192] -> Wt [8192][2048]
    wt_kernel<<<dim3(8192 / 32, 2048 / 32), dim3(32, 8), 0, stream>>>(fc_w, Wt, 2048, 8192);
    // 8. a = gelu(h2 @ fc_w + fc_b) (bf16 out)
    gemm_bt<1, 1><<<dim3(64, 64), 256, 0, stream>>>(X1, Wt, fc_b, Abuf, 8192, 8192, 2048);
    // 9. proj_w [8192][2048] -> Wt [2048][8192]
    wt_kernel<<<dim3(2048 / 32, 8192 / 32), dim3(32, 8), 0, stream>>>(proj_w, Wt, 8192, 2048);
    // 10. out = a @ proj_w + proj_b (f32 out)
    gemm_bt<0, 0><<<dim3(16, 64), 256, 0, stream>>>(Abuf, Wt, proj_b, out, 8192, 2048, 8192);
}

// Round 3
// 1045.340 us; speedup vs baseline: 1.6357x; 1.3432x over previous
//
#include <hip/hip_runtime.h>
#include <hip/hip_bf16.h>

// ---------- types & helpers ----------
typedef __attribute__((ext_vector_type(8))) short      bf16x8;  // 8 bf16 = 4 VGPRs
typedef __attribute__((ext_vector_type(4))) float      f32x4;
typedef __attribute__((ext_vector_type(8))) unsigned short u16x8;

__device__ __forceinline__ unsigned short f2bf(float f) {
    union { __hip_bfloat16 h; unsigned short u; } cv;
    cv.h = __float2bfloat16(f);
    return cv.u;
}
__device__ __forceinline__ float bf2f(unsigned short u) {
    union { float f; unsigned int i; } cv;
    cv.i = ((unsigned int)u) << 16;
    return cv.f;
}
__device__ __forceinline__ void gload_lds16(const void* g, void* l) {
    __builtin_amdgcn_global_load_lds(
        (const __attribute__((address_space(1))) void*)g,
        (__attribute__((address_space(3))) void*)l, 16, 0, 0);
}
__device__ __forceinline__ f32x4 mfma16(bf16x8 a, bf16x8 b, f32x4 c) {
    return __builtin_amdgcn_mfma_f32_16x16x32_bf16(a, b, c, 0, 0, 0);
}
__device__ __forceinline__ float gelu_f(float x) {
    return 0.5f * x * (1.0f + erff(x * 0.70710678118654752f));
}

#define S_BARRIER() asm volatile("s_barrier" ::: "memory")
#define LGKM0()     do { asm volatile("s_waitcnt lgkmcnt(0)" ::: "memory"); \
                         __builtin_amdgcn_sched_barrier(0); } while (0)

// ---------- LayerNorm: one block per row of 2048, out = bf16 ----------
template<int IN_BF16>
__global__ __launch_bounds__(256) void ln_kernel(const void* in, const float* w, const float* b,
                                                 unsigned short* out) {
    const int row = blockIdx.x;
    const int tid = threadIdx.x;
    float v[8];
    if constexpr (IN_BF16) {
        const unsigned short* p = (const unsigned short*)in + (size_t)row * 2048 + tid * 8;
        u16x8 raw = *(const u16x8*)p;
#pragma unroll
        for (int j = 0; j < 8; j++) v[j] = bf2f(raw[j]);
    } else {
        const float* p = (const float*)in + (size_t)row * 2048 + tid * 8;
        float4 a = ((const float4*)p)[0];
        float4 c = ((const float4*)p)[1];
        v[0] = a.x; v[1] = a.y; v[2] = a.z; v[3] = a.w;
        v[4] = c.x; v[5] = c.y; v[6] = c.z; v[7] = c.w;
    }
    float s = 0.f, ss = 0.f;
#pragma unroll
    for (int j = 0; j < 8; j++) { s += v[j]; ss += v[j] * v[j]; }
#pragma unroll
    for (int off = 32; off > 0; off >>= 1) {
        s  += __shfl_xor(s, off);
        ss += __shfl_xor(ss, off);
    }
    __shared__ float red[8];
    const int wid = tid >> 6, lane = tid & 63;
    if (lane == 0) { red[wid] = s; red[4 + wid] = ss; }
    __syncthreads();
    s  = red[0] + red[1] + red[2] + red[3];
    ss = red[4] + red[5] + red[6] + red[7];
    const float mean = s * (1.0f / 2048.0f);
    const float var  = ss * (1.0f / 2048.0f) - mean * mean;
    const float rstd = rsqrtf(var + 1e-5f);
    unsigned short* op = out + (size_t)row * 2048 + tid * 8;
    u16x8 ov;
#pragma unroll
    for (int j = 0; j < 8; j++) {
        int c = tid * 8 + j;
        ov[j] = f2bf((v[j] - mean) * rstd * w[c] + b[c]);
    }
    *(u16x8*)op = ov;
}

// ---------- Weight transpose+convert: W[K][N] f32 -> WT[N][K] bf16 ----------
__global__ __launch_bounds__(256) void wt_kernel(const float* W, unsigned short* WT, int K, int N) {
    __shared__ unsigned short sm[32][33];
    const int n0 = blockIdx.x * 32, k0 = blockIdx.y * 32;
    const int tx = threadIdx.x, ty = threadIdx.y;
#pragma unroll
    for (int i = 0; i < 4; i++) {
        int k = ty + i * 8;
        sm[k][tx] = f2bf(W[(size_t)(k0 + k) * N + n0 + tx]);
    }
    __syncthreads();
#pragma unroll
    for (int i = 0; i < 4; i++) {
        int n = ty + i * 8;
        WT[(size_t)(n0 + n) * K + k0 + tx] = sm[tx][n];
    }
}

// ---------- V transpose: qkv bf16 -> vT[b][h][128][2048] bf16 ----------
__global__ __launch_bounds__(256) void vt_kernel(const unsigned short* qkv, unsigned short* vT) {
    __shared__ unsigned short sm[32][33];
    const int t0 = blockIdx.x * 32, d0 = blockIdx.y * 32, bh = blockIdx.z;
    const int b = bh >> 4, h = bh & 15;
    const int tx = threadIdx.x, ty = threadIdx.y;
#pragma unroll
    for (int i = 0; i < 4; i++) {
        int t = ty + i * 8;
        sm[t][tx] = qkv[(size_t)(b * 2048 + t0 + t) * 6144 + 4096 + h * 128 + d0 + tx];
    }
    __syncthreads();
#pragma unroll
    for (int i = 0; i < 4; i++) {
        int d = ty + i * 8;
        vT[(size_t)(bh * 128 + d0 + d) * 2048 + t0 + tx] = sm[tx][d];
    }
}

// ---------- GEMM 256x256 8-phase: C[M][N] = A[M][K] * BT[N][K]^T + bias ----------
// 512 thr (8 waves 2Mx4N), BK=64, double-buffered LDS (128KB), counted vmcnt,
// st-swizzled LDS (byte ^= (row&7)<<4, both-sides), setprio around MFMA.
template<int OUT_BF16, int ACT_GELU>
__global__ __launch_bounds__(512, 2) void gemm256(const unsigned short* __restrict__ A,
                                                  const unsigned short* __restrict__ BT,
                                                  const float* __restrict__ bias,
                                                  void* __restrict__ Cout,
                                                  int M, int N, int K) {
    __shared__ unsigned short As[2][256 * 64];
    __shared__ unsigned short Bs[2][256 * 64];
    const int tid = threadIdx.x;
    // bijective XCD-aware swizzle (all grids here are %8==0)
    const int gx = gridDim.x;
    const int lin = blockIdx.y * gx + blockIdx.x;
    const int cpx = (gx * gridDim.y) >> 3;
    const int swz = (lin & 7) * cpx + (lin >> 3);
    const int n0 = (swz % gx) * 256, m0 = (swz / gx) * 256;

    const int wid = tid >> 6, lane = tid & 63;
    const int wr = wid >> 2, wc = wid & 3;          // wave = 128-row x 64-col sub-tile
    const int lg = lane >> 4, l15 = lane & 15;
    const int nkt = K >> 6;

    // staging geometry: idx = i*512+tid, r = idx>>3 (0..127), slot = idx&7.
    // source col chunk = slot ^ (r&7)  (inverse-swizzle on global, linear LDS dest)
    const int sr = tid >> 3;                        // rows 0..63 (i=0); +64 (i=1)
    const int scol = ((tid & 7) ^ (sr & 7)) * 8;    // (sr+64)&7 == sr&7
    const int sdst = tid * 8;                       // ushort offset; +4096 for i=1

    auto stageA = [&](int ta, int h) {
        const unsigned short* g = A + (size_t)(m0 + h * 128 + sr) * K + ta * 64 + scol;
        unsigned short* d = &As[ta & 1][h * 8192 + sdst];
        gload_lds16(g, d);
        gload_lds16(g + (size_t)64 * K, d + 4096);
    };
    auto stageB = [&](int ta, int h) {
        const unsigned short* g = BT + (size_t)(n0 + h * 128 + sr) * K + ta * 64 + scol;
        unsigned short* d = &Bs[ta & 1][h * 8192 + sdst];
        gload_lds16(g, d);
        gload_lds16(g + (size_t)64 * K, d + 4096);
    };

    // prologue: t0 {A0,A1,B0,B1}, t1 {A0,A1}; per-wave vmcnt(4) -> t0 landed
    stageA(0, 0); stageA(0, 1); stageB(0, 0); stageB(0, 1);
    if (nkt > 1) {
        stageA(1, 0); stageA(1, 1);
        asm volatile("s_waitcnt vmcnt(4)" ::: "memory");
    } else {
        asm volatile("s_waitcnt vmcnt(0)" ::: "memory");
    }
    S_BARRIER();

    f32x4 acc[8][4] = {};
    const int lxor = l15 & 7;
    const int co0 = (lg ^ lxor) * 8;        // kk=0 chunk (k 0..31)
    const int co1 = ((4 + lg) ^ lxor) * 8;  // kk=1 chunk (k 32..63)
    const int arow = wr * 128 + l15;
    const int brow = wc * 64 + l15;

    for (int t = 0; t < nkt; ++t) {
        const int p = t & 1;
        const unsigned short* Ap = As[p];
        const unsigned short* Bp = Bs[p];
        bf16x8 af0[8], af1[8], bq0, bq1;

        // ---- P0: read ALL A frags + B(n0,n1,kk0); stage t+1 B0,B1 ----
#pragma unroll
        for (int m = 0; m < 8; m++) {
            const int rb = (arow + m * 16) * 64;
            af0[m] = *(const bf16x8*)&Ap[rb + co0];
            af1[m] = *(const bf16x8*)&Ap[rb + co1];
        }
        bq0 = *(const bf16x8*)&Bp[(brow) * 64 + co0];
        bq1 = *(const bf16x8*)&Bp[(brow + 16) * 64 + co0];
        if (t + 1 < nkt) { stageB(t + 1, 0); stageB(t + 1, 1); }
        S_BARRIER();
        LGKM0();   // drains all A reads too -> As[p] dead after this phase
        __builtin_amdgcn_s_setprio(1);
#pragma unroll
        for (int m = 0; m < 8; m++) {
            acc[m][0] = mfma16(af0[m], bq0, acc[m][0]);
            acc[m][1] = mfma16(af0[m], bq1, acc[m][1]);
        }
        __builtin_amdgcn_s_setprio(0);
        S_BARRIER();

        // ---- P1: read B(n2,n3,kk0); stage t+2 A0 (As[p] half0 is dead) ----
        bq0 = *(const bf16x8*)&Bp[(brow + 32) * 64 + co0];
        bq1 = *(const bf16x8*)&Bp[(brow + 48) * 64 + co0];
        if (t + 2 < nkt) stageA(t + 2, 0);
        S_BARRIER();
        LGKM0();
        __builtin_amdgcn_s_setprio(1);
#pragma unroll
        for (int m = 0; m < 8; m++) {
            acc[m][2] = mfma16(af0[m], bq0, acc[m][2]);
            acc[m][3] = mfma16(af0[m], bq1, acc[m][3]);
        }
        __builtin_amdgcn_s_setprio(0);
        S_BARRIER();

        // ---- P2: read B(n0,n1,kk1); stage t+2 A1 ----
        bq0 = *(const bf16x8*)&Bp[(brow) * 64 + co1];
        bq1 = *(const bf16x8*)&Bp[(brow + 16) * 64 + co1];
        if (t + 2 < nkt) stageA(t + 2, 1);
        S_BARRIER();
        LGKM0();
        __builtin_amdgcn_s_setprio(1);
#pragma unroll
        for (int m = 0; m < 8; m++) {
            acc[m][0] = mfma16(af1[m], bq0, acc[m][0]);
            acc[m][1] = mfma16(af1[m], bq1, acc[m][1]);
        }
        __builtin_amdgcn_s_setprio(0);
        S_BARRIER();

        // ---- P3: read B(n2,n3,kk1); counted vmcnt; no stage ----
        bq0 = *(const bf16x8*)&Bp[(brow + 32) * 64 + co1];
        bq1 = *(const bf16x8*)&Bp[(brow + 48) * 64 + co1];
        S_BARRIER();
        LGKM0();
        __builtin_amdgcn_s_setprio(1);
#pragma unroll
        for (int m = 0; m < 8; m++) {
            acc[m][2] = mfma16(af1[m], bq0, acc[m][2]);
            acc[m][3] = mfma16(af1[m], bq1, acc[m][3]);
        }
        __builtin_amdgcn_s_setprio(0);
        // t+1's {A0,A1,B0,B1} must be landed before next P0; leave t+2's A in flight
        if (t + 2 < nkt)      asm volatile("s_waitcnt vmcnt(4)" ::: "memory");
        else if (t + 1 < nkt) asm volatile("s_waitcnt vmcnt(0)" ::: "memory");
        S_BARRIER();
    }

    // ---- epilogue ----
#pragma unroll
    for (int n = 0; n < 4; n++) {
        const int col = n0 + wc * 64 + n * 16 + l15;
        const float bv = bias[col];
#pragma unroll
        for (int m = 0; m < 8; m++) {
            const int rbase = m0 + wr * 128 + m * 16 + lg * 4;
#pragma unroll
            for (int r = 0; r < 4; r++) {
                float v = acc[m][n][r] + bv;
                if (ACT_GELU) v = gelu_f(v);
                if (OUT_BF16)
                    ((unsigned short*)Cout)[(size_t)(rbase + r) * N + col] = f2bf(v);
                else
                    ((float*)Cout)[(size_t)(rbase + r) * N + col] = v;
            }
        }
    }
}

// ---------- Flash attention (causal), KVBLK=64, XOR-swizzled LDS ----------
__global__ __launch_bounds__(256) void attn_kernel(const unsigned short* __restrict__ qkv,
                                                   const unsigned short* __restrict__ vT,
                                                   unsigned short* __restrict__ y) {
    __shared__ unsigned short Qs[64 * 128];   // aliased as per-wave P after q-frag load
    __shared__ unsigned short Ks[64 * 128];
    __shared__ unsigned short VTs[128 * 64];
    const int pair = blockIdx.x, h = blockIdx.y, b = blockIdx.z;
    const int tid = threadIdx.x, wid = tid >> 6, lane = tid & 63;
    const int lg = lane >> 4, l15 = lane & 15;
    const float scale = 0.08838834764831845f;  // 1/sqrt(128)
    unsigned short* Ps = &Qs[wid * 1024];      // per-wave [16][64] swizzled

    for (int pass = 0; pass < 2; pass++) {
        const int qt = (pass == 0) ? (31 - pair) : pair;
        __syncthreads();  // previous pass fully consumed Q/P region
#pragma unroll
        for (int i = 0; i < 4; i++) {
            int idx = tid + 256 * i;
            int row = idx >> 4, ch = idx & 15;
            const unsigned short* g = qkv + (size_t)(b * 2048 + qt * 64 + row) * 6144
                                      + h * 128 + ((ch ^ (row & 7)) * 8);
            gload_lds16(g, &Qs[idx * 8]);
        }
        __syncthreads();
        const int rq = wid * 16 + l15;
        bf16x8 qf[4];
#pragma unroll
        for (int c = 0; c < 4; c++)
            qf[c] = *(const bf16x8*)&Qs[rq * 128 + (((c * 4 + lg) ^ (rq & 7)) * 8)];

        float m_run[4], l_run[4];
#pragma unroll
        for (int r = 0; r < 4; r++) { m_run[r] = -1e30f; l_run[r] = 0.f; }
        f32x4 O[8] = {};

        const int nkb = qt + 1;
        for (int kb = 0; kb < nkb; kb++) {
            __syncthreads();
#pragma unroll
            for (int i = 0; i < 4; i++) {
                int idx = tid + 256 * i;
                int row = idx >> 4, ch = idx & 15;
                const unsigned short* g = qkv + (size_t)(b * 2048 + kb * 64 + row) * 6144
                                          + 2048 + h * 128 + ((ch ^ (row & 7)) * 8);
                gload_lds16(g, &Ks[idx * 8]);
            }
#pragma unroll
            for (int i = 0; i < 4; i++) {
                int idx = tid + 256 * i;
                int row = idx >> 3, ch = idx & 7;
                const unsigned short* g = vT + (size_t)((b * 16 + h) * 128 + row) * 2048
                                          + kb * 64 + ((ch ^ (row & 7)) * 8);
                gload_lds16(g, &VTs[idx * 8]);
            }
            __syncthreads();

            f32x4 S[4] = {};
#pragma unroll
            for (int n = 0; n < 4; n++) {
                const int rk = n * 16 + l15;
#pragma unroll
                for (int c = 0; c < 4; c++) {
                    bf16x8 kf = *(const bf16x8*)&Ks[rk * 128 + (((c * 4 + lg) ^ (rk & 7)) * 8)];
                    S[n] = mfma16(qf[c], kf, S[n]);
                }
            }

            const int qgb = qt * 64 + wid * 16 + lg * 4;
#pragma unroll
            for (int r = 0; r < 4; r++) {
                const int qg = qgb + r;
                float sv[4];
#pragma unroll
                for (int n = 0; n < 4; n++) {
                    const int kg = kb * 64 + n * 16 + l15;
                    sv[n] = (kg <= qg) ? S[n][r] * scale : -1e30f;
                }
                float mx = fmaxf(fmaxf(sv[0], sv[1]), fmaxf(sv[2], sv[3]));
                mx = fmaxf(mx, __shfl_xor(mx, 1));
                mx = fmaxf(mx, __shfl_xor(mx, 2));
                mx = fmaxf(mx, __shfl_xor(mx, 4));
                mx = fmaxf(mx, __shfl_xor(mx, 8));
                const float mnew = fmaxf(m_run[r], mx);
                const float f = __expf(m_run[r] - mnew);
                const float p0 = __expf(sv[0] - mnew), p1 = __expf(sv[1] - mnew);
                const float p2 = __expf(sv[2] - mnew), p3 = __expf(sv[3] - mnew);
                float rs = (p0 + p1) + (p2 + p3);
                rs += __shfl_xor(rs, 1);
                rs += __shfl_xor(rs, 2);
                rs += __shfl_xor(rs, 4);
                rs += __shfl_xor(rs, 8);
                l_run[r] = l_run[r] * f + rs;
                m_run[r] = mnew;
#pragma unroll
                for (int n2 = 0; n2 < 8; n2++) O[n2][r] *= f;
                const int prow = lg * 4 + r;
                const int pxor = (prow & 7) << 3;
                Ps[(prow * 64 + l15) ^ pxor]      = f2bf(p0);
                Ps[(prow * 64 + 16 + l15) ^ pxor] = f2bf(p1);
                Ps[(prow * 64 + 32 + l15) ^ pxor] = f2bf(p2);
                Ps[(prow * 64 + 48 + l15) ^ pxor] = f2bf(p3);
            }

#pragma unroll
            for (int kk = 0; kk < 2; kk++) {
                bf16x8 pf = *(const bf16x8*)&Ps[l15 * 64 + (((kk * 4 + lg) ^ (l15 & 7)) * 8)];
#pragma unroll
                for (int n2 = 0; n2 < 8; n2++) {
                    const int rv = n2 * 16 + l15;
                    bf16x8 vf = *(const bf16x8*)&VTs[rv * 64 + (((kk * 4 + lg) ^ (rv & 7)) * 8)];
                    O[n2] = mfma16(pf, vf, O[n2]);
                }
            }
        }

#pragma unroll
        for (int r = 0; r < 4; r++) {
            const float inv = 1.0f / l_run[r];
            const size_t row = (size_t)(b * 2048 + qt * 64 + wid * 16 + lg * 4 + r);
#pragma unroll
            for (int n2 = 0; n2 < 8; n2++)
                y[row * 2048 + h * 128 + n2 * 16 + l15] = f2bf(O[n2][r] * inv);
        }
    }
}

// ---------- launcher ----------
extern "C" void kernel_launch(void* const* d_in, const int* in_sizes, int n_in,
                              void* d_out, int out_size, void* d_ws, size_t ws_size,
                              hipStream_t stream) {
    const float* x      = (const float*)d_in[0];
    const float* ln1_w  = (const float*)d_in[1];
    const float* ln1_b  = (const float*)d_in[2];
    const float* attn_w = (const float*)d_in[3];
    const float* attn_b = (const float*)d_in[4];
    const float* ln2_w  = (const float*)d_in[5];
    const float* ln2_b  = (const float*)d_in[6];
    const float* fc_w   = (const float*)d_in[7];
    const float* fc_b   = (const float*)d_in[8];
    const float* proj_w = (const float*)d_in[9];
    const float* proj_b = (const float*)d_in[10];
    float* out = (float*)d_out;

    char* ws = (char*)d_ws;
    const size_t MB = 1024ull * 1024ull;
    unsigned short* Wt   = (unsigned short*)(ws + 0);         // 32MB: transposed weight (per phase)
    unsigned short* X1   = (unsigned short*)(ws + 32 * MB);   // 32MB: h / h2
    unsigned short* X2   = (unsigned short*)(ws + 64 * MB);   // 32MB: y
    unsigned short* QKV  = (unsigned short*)(ws + 96 * MB);   // 96MB: qkv bf16
    unsigned short* VT   = (unsigned short*)(ws + 192 * MB);  // 32MB: vT
    unsigned short* Abuf = (unsigned short*)(ws + 96 * MB);   // 128MB: gelu(fc) (reuses QKV+VT)

    // 1. h = ln1(x)
    ln_kernel<0><<<8192, 256, 0, stream>>>(x, ln1_w, ln1_b, X1);
    // 2. attn_w [2048][6144] -> Wt [6144][2048] bf16
    wt_kernel<<<dim3(6144 / 32, 2048 / 32), dim3(32, 8), 0, stream>>>(attn_w, Wt, 2048, 6144);
    // 3. qkv = h @ attn_w + attn_b  (bf16 out)
    gemm256<1, 0><<<dim3(24, 32), 512, 0, stream>>>(X1, Wt, attn_b, QKV, 8192, 6144, 2048);
    // 4. vT
    vt_kernel<<<dim3(64, 4, 64), dim3(32, 8), 0, stream>>>(QKV, VT);
    // 5. y = causal_attention(q,k,v)
    attn_kernel<<<dim3(16, 16, 4), 256, 0, stream>>>(QKV, VT, X2);
    // 6. h2 = ln2(y)
    ln_kernel<1><<<8192, 256, 0, stream>>>(X2, ln2_w, ln2_b, X1);
    // 7. fc_w [2048][8192] -> Wt [8192][2048]
    wt_kernel<<<dim3(8192 / 32, 2048 / 32), dim3(32, 8), 0, stream>>>(fc_w, Wt, 2048, 8192);
    // 8. a = gelu(h2 @ fc_w + fc_b) (bf16 out)
    gemm256<1, 1><<<dim3(32, 32), 512, 0, stream>>>(X1, Wt, fc_b, Abuf, 8192, 8192, 2048);
    // 9. proj_w [8192][2048] -> Wt [2048][8192]
    wt_kernel<<<dim3(2048 / 32, 8192 / 32), dim3(32, 8), 0, stream>>>(proj_w, Wt, 8192, 2048);
    // 10. out = a @ proj_w + proj_b (f32 out)
    gemm256<0, 0><<<dim3(8, 32), 512, 0, stream>>>(Abuf, Wt, proj_b, out, 8192, 2048, 8192);
}